// Round 1
// baseline (587.614 us; speedup 1.0000x reference)
//
#include <hip/hip_runtime.h>
#include <stdint.h>

typedef __attribute__((ext_vector_type(8))) short bf16x8;
typedef __attribute__((ext_vector_type(4))) float f32x4;

#define NE 320000
#define NNODES 20000
#define SMEM_BYTES (65536 + 16384 + 32768)

__device__ __forceinline__ unsigned short f2bf(float f) {
  union { float f; unsigned int u; } v; v.f = f;
  unsigned int u = v.u;
  u += 0x7fffu + ((u >> 16) & 1u);   // round-to-nearest-even
  return (unsigned short)(u >> 16);
}

__device__ __forceinline__ void gload_lds16(const void* g, void* l) {
  __builtin_amdgcn_global_load_lds((const __attribute__((address_space(1))) void*)g,
                                   (__attribute__((address_space(3))) void*)l, 16, 0, 0);
}

// stage `nbytes` (multiple of 8192) linearly global->LDS; 1KB per wave-issue
__device__ __forceinline__ void stage_b(const unsigned short* gsrc, char* lds, int nbytes,
                                        int w, int lane) {
  const char* gp = (const char*)gsrc + lane * 16;
  int niss = nbytes >> 10;
#pragma unroll
  for (int i = 0; i < 4; ++i) {
    int idx = w + i * 8;
    if (idx < niss) gload_lds16(gp + (idx << 10), lds + (idx << 10));
  }
}

// ---- weight packing: W[K][N] fp32 -> bf16 packed [(k/8)][N][8] (B-fragment order) ----
struct PackArgs {
  const float* src[8];
  unsigned short* dst[8];
  int K[8];
  int N[8];
};

__global__ void pack_weights(PackArgs a) {
  int m = blockIdx.y;
  int K = a.K[m], N = a.N[m];
  int total = (K >> 3) * N;
  int idx = blockIdx.x * 256 + threadIdx.x;
  if (idx >= total) return;
  int n = idx % N;
  int kg = idx / N;
  const float* s = a.src[m];
  bf16x8 p;
#pragma unroll
  for (int j = 0; j < 8; ++j)
    p[j] = (short)f2bf(s[(size_t)(kg * 8 + j) * N + n]);
  *(bf16x8*)(a.dst[m] + (size_t)idx * 8) = p;
}

// compute 2 k-steps (one 64-wide K chunk) of MFMAs
template <int NB>
__device__ __forceinline__ void compute_chunk(const char* Ab, int rowstride, int kbyte0,
                                              const char* Bb, int NN, int colbase,
                                              int wm, int lhi, int llo, f32x4 (&acc)[2][8]) {
#pragma unroll
  for (int ks = 0; ks < 2; ++ks) {
    bf16x8 a[2];
#pragma unroll
    for (int m = 0; m < 2; ++m) {
      int row = wm * 32 + m * 16 + llo;
      int off = (row * rowstride + kbyte0 + ks * 64 + lhi * 16) ^ ((row & 7) << 4);
      a[m] = *(const bf16x8*)(Ab + off);
    }
    bf16x8 b[NB];
#pragma unroll
    for (int n = 0; n < NB; ++n) {
      int off = ((ks * 4 + lhi) * NN + colbase + n * 16 + llo) * 16;
      b[n] = *(const bf16x8*)(Bb + off);
    }
#pragma unroll
    for (int m = 0; m < 2; ++m)
#pragma unroll
      for (int n = 0; n < NB; ++n)
        acc[m][n] = __builtin_amdgcn_mfma_f32_16x16x32_bf16(a[m], b[n], acc[m][n], 0, 0, 0);
  }
}

__device__ __forceinline__ void zero_acc(f32x4 (&acc)[2][8]) {
  f32x4 z = {0.f, 0.f, 0.f, 0.f};
#pragma unroll
  for (int m = 0; m < 2; ++m)
#pragma unroll
    for (int n = 0; n < 8; ++n) acc[m][n] = z;
}

// write relu(acc+bias) as bf16 into swizzled H [128][256]
__device__ __forceinline__ void write_h(char* Hb, const f32x4 (&acc)[2][8], const float* bias,
                                        int wm, int wn, int lhi, int llo) {
#pragma unroll
  for (int n = 0; n < 8; ++n) {
    int col = wn * 128 + n * 16 + llo;
    float bv = bias[col];
#pragma unroll
    for (int m = 0; m < 2; ++m)
#pragma unroll
      for (int q = 0; q < 4; ++q) {
        int row = wm * 32 + m * 16 + lhi * 4 + q;
        float v = fmaxf(acc[m][n][q] + bv, 0.0f);
        int off = (row * 512 + col * 2) ^ ((row & 7) << 4);
        *(unsigned short*)(Hb + off) = f2bf(v);
      }
  }
}

// MODE 0: edge MLP (K1=512, gather [g|nodes[s]|nodes[r]|edges], agg atomics, e_sum)
// MODE 1: node MLP (K1=384, gather [g|nodes|agg], n_sum)
template <int MODE>
__global__ __launch_bounds__(512, 2) void fused_mlp(
    const float* __restrict__ gvec, const float* __restrict__ nodes,
    const float* __restrict__ third, const int* __restrict__ senders,
    const int* __restrict__ receivers,
    const unsigned short* __restrict__ pw1, const unsigned short* __restrict__ pw2,
    const unsigned short* __restrict__ pw3, const unsigned short* __restrict__ pw4,
    const float* __restrict__ b1, const float* __restrict__ b2,
    const float* __restrict__ b3, const float* __restrict__ b4,
    float* __restrict__ outp, float* __restrict__ aggp, float* __restrict__ colsum) {
  constexpr int K1 = (MODE == 0) ? 512 : 384;
  constexpr int KC1 = K1 / 64;
  constexpr int NROWS = (MODE == 0) ? NE : NNODES;

  extern __shared__ char smem[];
  char* Hb = smem;            // 65536: H [128][256] bf16, XOR-swizzled
  char* Ab = smem + 65536;    // 16384: layer-1 A chunk [128][64] bf16, swizzled
  char* Bb = smem + 81920;    // 32768: packed-B chunk

  const int tid = threadIdx.x;
  const int lane = tid & 63;
  const int w = tid >> 6;
  const int wm = w & 3, wn = w >> 2;
  const int lhi = lane >> 4, llo = lane & 15;
  const int row0 = blockIdx.x * 128;

  // gather setup: thread handles row (tid>>2), 16-col group (tid&3)
  const int grow = tid >> 2;
  const int qq = tid & 3;
  const float* src0 = gvec;
  const float* src1;
  const float* src2;
  const float* src3;
  if (MODE == 0) {
    int e = row0 + grow;
    src1 = nodes + (size_t)senders[e] * 128;
    src2 = nodes + (size_t)receivers[e] * 128;
    src3 = third + (size_t)e * 128;
  } else {
    int i = row0 + grow;
    bool v = i < NROWS;
    src1 = v ? nodes + (size_t)i * 128 : gvec;
    src2 = v ? third + (size_t)i * 128 : gvec;
    src3 = gvec;
  }

  f32x4 acc[2][8];
  zero_acc(acc);

  // ---------------- layer 1 ----------------
  for (int c = 0; c < KC1; ++c) {
    {
      int gc = c * 64 + qq * 16;
      int region = gc >> 7;
      const float* sp = (region == 0) ? src0 : (region == 1) ? src1 : (region == 2) ? src2 : src3;
      sp += (gc & 127);
      f32x4 v0 = *(const f32x4*)(sp);
      f32x4 v1 = *(const f32x4*)(sp + 4);
      f32x4 v2 = *(const f32x4*)(sp + 8);
      f32x4 v3 = *(const f32x4*)(sp + 12);
      bf16x8 p0, p1;
#pragma unroll
      for (int j = 0; j < 4; ++j) {
        p0[j] = (short)f2bf(v0[j]);
        p0[4 + j] = (short)f2bf(v1[j]);
        p1[j] = (short)f2bf(v2[j]);
        p1[4 + j] = (short)f2bf(v3[j]);
      }
      int ab = grow * 128 + qq * 32;
      int sw = (grow & 7) << 4;
      *(bf16x8*)(Ab + (ab ^ sw)) = p0;
      *(bf16x8*)(Ab + ((ab + 16) ^ sw)) = p1;
    }
    stage_b(pw1 + (size_t)c * 16384, Bb, 32768, w, lane);
    __syncthreads();
    compute_chunk<8>(Ab, 128, 0, Bb, 256, wn * 128, wm, lhi, llo, acc);
    __syncthreads();
  }
  write_h(Hb, acc, b1, wm, wn, lhi, llo);
  __syncthreads();

  // ---------------- layer 2 ----------------
  zero_acc(acc);
  for (int c = 0; c < 4; ++c) {
    stage_b(pw2 + (size_t)c * 16384, Bb, 32768, w, lane);
    __syncthreads();
    compute_chunk<8>(Hb, 512, c * 128, Bb, 256, wn * 128, wm, lhi, llo, acc);
    __syncthreads();
  }
  write_h(Hb, acc, b2, wm, wn, lhi, llo);
  __syncthreads();

  // ---------------- layer 3 ----------------
  zero_acc(acc);
  for (int c = 0; c < 4; ++c) {
    stage_b(pw3 + (size_t)c * 16384, Bb, 32768, w, lane);
    __syncthreads();
    compute_chunk<8>(Hb, 512, c * 128, Bb, 256, wn * 128, wm, lhi, llo, acc);
    __syncthreads();
  }
  write_h(Hb, acc, b3, wm, wn, lhi, llo);
  __syncthreads();

  // ---------------- layer 4 (N=128, linear) ----------------
  zero_acc(acc);
  for (int c = 0; c < 4; ++c) {
    stage_b(pw4 + (size_t)c * 8192, Bb, 16384, w, lane);
    __syncthreads();
    compute_chunk<4>(Hb, 512, c * 128, Bb, 128, wn * 64, wm, lhi, llo, acc);
    __syncthreads();
  }

  // epilogue: store fp32, fused segment-sum atomics (edge), column sums
  float cs[4] = {0.f, 0.f, 0.f, 0.f};
#pragma unroll
  for (int n = 0; n < 4; ++n) {
    int col = wn * 64 + n * 16 + llo;
    float bv = b4[col];
#pragma unroll
    for (int m = 0; m < 2; ++m)
#pragma unroll
      for (int q = 0; q < 4; ++q) {
        int gr = row0 + wm * 32 + m * 16 + lhi * 4 + q;
        float v = acc[m][n][q] + bv;
        if (MODE == 0) {
          outp[(size_t)gr * 128 + col] = v;
          atomicAdd(aggp + (size_t)receivers[gr] * 128 + col, v);
          cs[n] += v;
        } else {
          if (gr < NROWS) {
            outp[(size_t)gr * 128 + col] = v;
            cs[n] += v;
          }
        }
      }
  }
#pragma unroll
  for (int n = 0; n < 4; ++n) {
    float v = cs[n];
    v += __shfl_xor(v, 16);
    v += __shfl_xor(v, 32);
    if (lane < 16) atomicAdd(colsum + wn * 64 + n * 16 + llo, v);
  }
}

// tiny fp32 global MLP: x = [g | n_sum | e_sum]
__global__ void global_mlp(const float* __restrict__ g, const float* __restrict__ nsum,
                           const float* __restrict__ esum, const float* __restrict__ w1,
                           const float* __restrict__ bb1, const float* __restrict__ w2,
                           const float* __restrict__ bb2, const float* __restrict__ w3,
                           const float* __restrict__ bb3, const float* __restrict__ w4,
                           const float* __restrict__ bb4, float* __restrict__ outg) {
  __shared__ float x[384], h1[256], h2[256], h3[256];
  int t = threadIdx.x;
  if (t < 128) x[t] = g[t];
  else if (t < 256) x[t] = nsum[t - 128];
  else x[t] = esum[t - 256];
  __syncthreads();
  if (t < 256) {
    float a = bb1[t];
    for (int k = 0; k < 384; ++k) a = fmaf(x[k], w1[k * 256 + t], a);
    h1[t] = fmaxf(a, 0.f);
  }
  __syncthreads();
  if (t < 256) {
    float a = bb2[t];
    for (int k = 0; k < 256; ++k) a = fmaf(h1[k], w2[k * 256 + t], a);
    h2[t] = fmaxf(a, 0.f);
  }
  __syncthreads();
  if (t < 256) {
    float a = bb3[t];
    for (int k = 0; k < 256; ++k) a = fmaf(h2[k], w3[k * 256 + t], a);
    h3[t] = fmaxf(a, 0.f);
  }
  __syncthreads();
  if (t < 128) {
    float a = bb4[t];
    for (int k = 0; k < 256; ++k) a = fmaf(h3[k], w4[k * 128 + t], a);
    outg[t] = a;
  }
}

extern "C" void kernel_launch(void* const* d_in, const int* in_sizes, int n_in, void* d_out,
                              int out_size, void* d_ws, size_t ws_size, hipStream_t stream) {
  const float* g = (const float*)d_in[0];
  const float* nodes = (const float*)d_in[1];
  const float* edges = (const float*)d_in[2];
  const int* senders = (const int*)d_in[3];
  const int* receivers = (const int*)d_in[4];
  const float* ew[4] = {(const float*)d_in[5], (const float*)d_in[7], (const float*)d_in[9],
                        (const float*)d_in[11]};
  const float* eb[4] = {(const float*)d_in[6], (const float*)d_in[8], (const float*)d_in[10],
                        (const float*)d_in[12]};
  const float* nw[4] = {(const float*)d_in[13], (const float*)d_in[15], (const float*)d_in[17],
                        (const float*)d_in[19]};
  const float* nb[4] = {(const float*)d_in[14], (const float*)d_in[16], (const float*)d_in[18],
                        (const float*)d_in[20]};
  const float* gw[4] = {(const float*)d_in[21], (const float*)d_in[23], (const float*)d_in[25],
                        (const float*)d_in[27]};
  const float* gb[4] = {(const float*)d_in[22], (const float*)d_in[24], (const float*)d_in[26],
                        (const float*)d_in[28]};

  float* out = (float*)d_out;
  float* e_new = out;
  float* n_new = out + (size_t)NE * 128;
  float* g_new = n_new + (size_t)NNODES * 128;

  // workspace layout
  char* ws = (char*)d_ws;
  unsigned short* pe1 = (unsigned short*)ws;           // 512x256
  unsigned short* pe2 = pe1 + 512 * 256;               // 256x256
  unsigned short* pe3 = pe2 + 256 * 256;               // 256x256
  unsigned short* pe4 = pe3 + 256 * 256;               // 256x128
  unsigned short* pn1 = pe4 + 256 * 128;               // 384x256
  unsigned short* pn2 = pn1 + 384 * 256;               // 256x256
  unsigned short* pn3 = pn2 + 256 * 256;               // 256x256
  unsigned short* pn4 = pn3 + 256 * 256;               // 256x128
  float* agg = (float*)(ws + 1114112);                 // 20000x128 fp32
  float* esum = agg + (size_t)NNODES * 128;            // 128
  float* nsum = esum + 128;                            // 128

  hipMemsetAsync(agg, 0, (size_t)NNODES * 128 * 4 + 1024, stream);

  PackArgs pa;
  const float* srcs[8] = {ew[0], ew[1], ew[2], ew[3], nw[0], nw[1], nw[2], nw[3]};
  unsigned short* dsts[8] = {pe1, pe2, pe3, pe4, pn1, pn2, pn3, pn4};
  int Ks[8] = {512, 256, 256, 256, 384, 256, 256, 256};
  int Ns[8] = {256, 256, 256, 128, 256, 256, 256, 128};
  for (int i = 0; i < 8; ++i) {
    pa.src[i] = srcs[i];
    pa.dst[i] = dsts[i];
    pa.K[i] = Ks[i];
    pa.N[i] = Ns[i];
  }
  pack_weights<<<dim3(64, 8), 256, 0, stream>>>(pa);

  hipFuncSetAttribute((const void*)&fused_mlp<0>, hipFuncAttributeMaxDynamicSharedMemorySize,
                      SMEM_BYTES);
  hipFuncSetAttribute((const void*)&fused_mlp<1>, hipFuncAttributeMaxDynamicSharedMemorySize,
                      SMEM_BYTES);

  fused_mlp<0><<<NE / 128, 512, SMEM_BYTES, stream>>>(
      g, nodes, edges, senders, receivers, pe1, pe2, pe3, pe4, eb[0], eb[1], eb[2], eb[3], e_new,
      agg, esum);
  fused_mlp<1><<<(NNODES + 127) / 128, 512, SMEM_BYTES, stream>>>(
      g, nodes, agg, senders, receivers, pn1, pn2, pn3, pn4, nb[0], nb[1], nb[2], nb[3], n_new,
      nullptr, nsum);
  global_mlp<<<1, 384, 0, stream>>>(g, nsum, esum, gw[0], gb[0], gw[1], gb[1], gw[2], gb[2], gw[3],
                                    gb[3], g_new);
}

// Round 2
// 556.623 us; speedup vs baseline: 1.0557x; 1.0557x over previous
//
#include <hip/hip_runtime.h>
#include <stdint.h>

typedef __attribute__((ext_vector_type(8))) short bf16x8;
typedef __attribute__((ext_vector_type(4))) float f32x4;

#define NE 320000
#define NNODES 20000
#define SMEM_BYTES 163840  // H 64K | A0 16K | A1 16K | B0 32K | B1 32K

__device__ __forceinline__ unsigned short f2bf(float f) {
  union { float f; unsigned int u; } v; v.f = f;
  unsigned int u = v.u;
  u += 0x7fffu + ((u >> 16) & 1u);   // round-to-nearest-even
  return (unsigned short)(u >> 16);
}

__device__ __forceinline__ void gload_lds16(const void* g, void* l) {
  __builtin_amdgcn_global_load_lds((const __attribute__((address_space(1))) void*)g,
                                   (__attribute__((address_space(3))) void*)l, 16, 0, 0);
}

// stage `nbytes` linearly global->LDS; 1KB per wave-issue (64 lanes x 16B)
__device__ __forceinline__ void stage_b(const unsigned short* gsrc, char* lds, int nbytes,
                                        int w, int lane) {
  const char* gp = (const char*)gsrc + lane * 16;
  int niss = nbytes >> 10;
#pragma unroll
  for (int i = 0; i < 4; ++i) {
    int idx = w + i * 8;
    if (idx < niss) gload_lds16(gp + (idx << 10), lds + (idx << 10));
  }
}

// ---- weight packing: W[K][N] fp32 -> bf16 packed [(k/8)][N][8] (B-fragment order) ----
struct PackArgs {
  const float* src[8];
  unsigned short* dst[8];
  int K[8];
  int N[8];
};

__global__ void pack_weights(PackArgs a) {
  int m = blockIdx.y;
  int K = a.K[m], N = a.N[m];
  int total = (K >> 3) * N;
  int idx = blockIdx.x * 256 + threadIdx.x;
  if (idx >= total) return;
  int n = idx % N;
  int kg = idx / N;
  const float* s = a.src[m];
  bf16x8 p;
#pragma unroll
  for (int j = 0; j < 8; ++j)
    p[j] = (short)f2bf(s[(size_t)(kg * 8 + j) * N + n]);
  *(bf16x8*)(a.dst[m] + (size_t)idx * 8) = p;
}

// compute 2 k-steps (one 64-wide K chunk) of MFMAs
template <int NB>
__device__ __forceinline__ void compute_chunk(const char* Ab, int rowstride, int kbyte0,
                                              const char* Bb, int NN, int colbase,
                                              int wm, int lhi, int llo, f32x4 (&acc)[2][8]) {
#pragma unroll
  for (int ks = 0; ks < 2; ++ks) {
    bf16x8 a[2];
#pragma unroll
    for (int m = 0; m < 2; ++m) {
      int row = wm * 32 + m * 16 + llo;
      int off = (row * rowstride + kbyte0 + ks * 64 + lhi * 16) ^ ((row & 7) << 4);
      a[m] = *(const bf16x8*)(Ab + off);
    }
    bf16x8 b[NB];
#pragma unroll
    for (int n = 0; n < NB; ++n) {
      int off = ((ks * 4 + lhi) * NN + colbase + n * 16 + llo) * 16;
      b[n] = *(const bf16x8*)(Bb + off);
    }
#pragma unroll
    for (int m = 0; m < 2; ++m)
#pragma unroll
      for (int n = 0; n < NB; ++n)
        acc[m][n] = __builtin_amdgcn_mfma_f32_16x16x32_bf16(a[m], b[n], acc[m][n], 0, 0, 0);
  }
}

__device__ __forceinline__ void zero_acc(f32x4 (&acc)[2][8]) {
  f32x4 z = {0.f, 0.f, 0.f, 0.f};
#pragma unroll
  for (int m = 0; m < 2; ++m)
#pragma unroll
    for (int n = 0; n < 8; ++n) acc[m][n] = z;
}

// write relu(acc+bias) as bf16 into swizzled H [128][256]
__device__ __forceinline__ void write_h(char* Hb, const f32x4 (&acc)[2][8], const float* bias,
                                        int wm, int wn, int lhi, int llo) {
#pragma unroll
  for (int n = 0; n < 8; ++n) {
    int col = wn * 128 + n * 16 + llo;
    float bv = bias[col];
#pragma unroll
    for (int m = 0; m < 2; ++m)
#pragma unroll
      for (int q = 0; q < 4; ++q) {
        int row = wm * 32 + m * 16 + lhi * 4 + q;
        float v = fmaxf(acc[m][n][q] + bv, 0.0f);
        int off = (row * 512 + col * 2) ^ ((row & 7) << 4);
        *(unsigned short*)(Hb + off) = f2bf(v);
      }
  }
}

__device__ __forceinline__ void gather_regs(int gc, const float* src0, const float* src1,
                                            const float* src2, const float* src3, f32x4 (&v)[4]) {
  int region = gc >> 7;
  const float* sp = (region == 0) ? src0 : (region == 1) ? src1 : (region == 2) ? src2 : src3;
  sp += (gc & 127);
  v[0] = *(const f32x4*)(sp);
  v[1] = *(const f32x4*)(sp + 4);
  v[2] = *(const f32x4*)(sp + 8);
  v[3] = *(const f32x4*)(sp + 12);
}

__device__ __forceinline__ void pack_write_A(char* Abuf, int grow, int qq, const f32x4 (&v)[4]) {
  bf16x8 p0, p1;
#pragma unroll
  for (int j = 0; j < 4; ++j) {
    p0[j] = (short)f2bf(v[0][j]);
    p0[4 + j] = (short)f2bf(v[1][j]);
    p1[j] = (short)f2bf(v[2][j]);
    p1[4 + j] = (short)f2bf(v[3][j]);
  }
  int ab = grow * 128 + qq * 32;
  int sw = (grow & 7) << 4;
  *(bf16x8*)(Abuf + (ab ^ sw)) = p0;
  *(bf16x8*)(Abuf + ((ab + 16) ^ sw)) = p1;
}

// MODE 0: edge MLP (K1=512, gather [g|nodes[s]|nodes[r]|edges], agg atomics, e_sum)
// MODE 1: node MLP (K1=384, gather [g|nodes|agg], n_sum)
template <int MODE>
__global__ __launch_bounds__(512) void fused_mlp(
    const float* __restrict__ gvec, const float* __restrict__ nodes,
    const float* __restrict__ third, const int* __restrict__ senders,
    const int* __restrict__ receivers,
    const unsigned short* __restrict__ pw1, const unsigned short* __restrict__ pw2,
    const unsigned short* __restrict__ pw3, const unsigned short* __restrict__ pw4,
    const float* __restrict__ b1, const float* __restrict__ b2,
    const float* __restrict__ b3, const float* __restrict__ b4,
    float* __restrict__ outp, float* __restrict__ aggp, float* __restrict__ colsum) {
  constexpr int K1 = (MODE == 0) ? 512 : 384;
  constexpr int KC1 = K1 / 64;  // 8 or 6 (even -> every layer starts on buffer parity 0)
  constexpr int NROWS = (MODE == 0) ? NE : NNODES;

  extern __shared__ char smem[];
  char* Hb = smem;              // 65536: H [128][256] bf16, XOR-swizzled
  char* Ab0 = smem + 65536;     // 16384: layer-1 A chunk ping
  char* Ab1 = smem + 81920;     // 16384: layer-1 A chunk pong
  char* Bb0 = smem + 98304;     // 32768: packed-B ping
  char* Bb1 = smem + 131072;    // 32768: packed-B pong

  const int tid = threadIdx.x;
  const int lane = tid & 63;
  const int w = tid >> 6;
  const int wm = w & 3, wn = w >> 2;
  const int lhi = lane >> 4, llo = lane & 15;
  const int row0 = blockIdx.x * 128;

  // gather setup: thread handles row (tid>>2), 16-col group (tid&3)
  const int grow = tid >> 2;
  const int qq = tid & 3;
  const float* src0 = gvec;
  const float* src1;
  const float* src2;
  const float* src3;
  if (MODE == 0) {
    int e = row0 + grow;
    src1 = nodes + (size_t)senders[e] * 128;
    src2 = nodes + (size_t)receivers[e] * 128;
    src3 = third + (size_t)e * 128;
  } else {
    int i = row0 + grow;
    bool v = i < NROWS;
    src1 = v ? nodes + (size_t)i * 128 : gvec;
    src2 = v ? third + (size_t)i * 128 : gvec;
    src3 = gvec;
  }

  f32x4 acc[2][8];
  zero_acc(acc);

  // ---------------- prologue: A(0) + B(0) ----------------
  {
    f32x4 v[4];
    gather_regs(qq * 16, src0, src1, src2, src3, v);
    pack_write_A(Ab0, grow, qq, v);
  }
  stage_b(pw1, Bb0, 32768, w, lane);
  __syncthreads();

  // ---------------- layer 1 (2-phase pipelined) ----------------
#pragma unroll
  for (int c = 0; c < KC1; ++c) {
    char* Bn = ((c + 1) & 1) ? Bb1 : Bb0;
    f32x4 v[4];
    if (c + 1 < KC1) {
      gather_regs((c + 1) * 64 + qq * 16, src0, src1, src2, src3, v);  // loads in flight
      stage_b(pw1 + (size_t)(c + 1) * 16384, Bn, 32768, w, lane);
    } else {
      stage_b(pw2, Bn, 32768, w, lane);  // prefetch layer-2 chunk 0 (lands in Bb0)
    }
    compute_chunk<8>((c & 1) ? Ab1 : Ab0, 128, 0, (c & 1) ? Bb1 : Bb0, 256, wn * 128, wm, lhi,
                     llo, acc);
    if (c + 1 < KC1) pack_write_A(((c + 1) & 1) ? Ab1 : Ab0, grow, qq, v);
    __syncthreads();
  }
  write_h(Hb, acc, b1, wm, wn, lhi, llo);
  __syncthreads();

  // ---------------- layer 2 ----------------
  zero_acc(acc);
#pragma unroll
  for (int c = 0; c < 4; ++c) {
    char* Bn = ((c + 1) & 1) ? Bb1 : Bb0;
    if (c < 3) stage_b(pw2 + (size_t)(c + 1) * 16384, Bn, 32768, w, lane);
    else stage_b(pw3, Bn, 32768, w, lane);
    compute_chunk<8>(Hb, 512, c * 128, (c & 1) ? Bb1 : Bb0, 256, wn * 128, wm, lhi, llo, acc);
    __syncthreads();
  }
  write_h(Hb, acc, b2, wm, wn, lhi, llo);
  __syncthreads();

  // ---------------- layer 3 ----------------
  zero_acc(acc);
#pragma unroll
  for (int c = 0; c < 4; ++c) {
    char* Bn = ((c + 1) & 1) ? Bb1 : Bb0;
    if (c < 3) stage_b(pw3 + (size_t)(c + 1) * 16384, Bn, 32768, w, lane);
    else stage_b(pw4, Bn, 16384, w, lane);  // layer-4 chunk 0
    compute_chunk<8>(Hb, 512, c * 128, (c & 1) ? Bb1 : Bb0, 256, wn * 128, wm, lhi, llo, acc);
    __syncthreads();
  }
  write_h(Hb, acc, b3, wm, wn, lhi, llo);
  __syncthreads();

  // ---------------- layer 4 (N=128, linear) ----------------
  zero_acc(acc);
#pragma unroll
  for (int c = 0; c < 4; ++c) {
    if (c < 3) stage_b(pw4 + (size_t)(c + 1) * 8192, ((c + 1) & 1) ? Bb1 : Bb0, 16384, w, lane);
    compute_chunk<4>(Hb, 512, c * 128, (c & 1) ? Bb1 : Bb0, 128, wn * 64, wm, lhi, llo, acc);
    __syncthreads();
  }

  // epilogue: store fp32, fused segment-sum atomics (edge), column sums
  float cs[4] = {0.f, 0.f, 0.f, 0.f};
#pragma unroll
  for (int n = 0; n < 4; ++n) {
    int col = wn * 64 + n * 16 + llo;
    float bv = b4[col];
#pragma unroll
    for (int m = 0; m < 2; ++m)
#pragma unroll
      for (int q = 0; q < 4; ++q) {
        int gr = row0 + wm * 32 + m * 16 + lhi * 4 + q;
        float v = acc[m][n][q] + bv;
        if (MODE == 0) {
          outp[(size_t)gr * 128 + col] = v;
          atomicAdd(aggp + (size_t)receivers[gr] * 128 + col, v);
          cs[n] += v;
        } else {
          if (gr < NROWS) {
            outp[(size_t)gr * 128 + col] = v;
            cs[n] += v;
          }
        }
      }
  }
#pragma unroll
  for (int n = 0; n < 4; ++n) {
    float v = cs[n];
    v += __shfl_xor(v, 16);
    v += __shfl_xor(v, 32);
    if (lane < 16) atomicAdd(colsum + wn * 64 + n * 16 + llo, v);
  }
}

// tiny fp32 global MLP: x = [g | n_sum | e_sum]
__global__ void global_mlp(const float* __restrict__ g, const float* __restrict__ nsum,
                           const float* __restrict__ esum, const float* __restrict__ w1,
                           const float* __restrict__ bb1, const float* __restrict__ w2,
                           const float* __restrict__ bb2, const float* __restrict__ w3,
                           const float* __restrict__ bb3, const float* __restrict__ w4,
                           const float* __restrict__ bb4, float* __restrict__ outg) {
  __shared__ float x[384], h1[256], h2[256], h3[256];
  int t = threadIdx.x;
  if (t < 128) x[t] = g[t];
  else if (t < 256) x[t] = nsum[t - 128];
  else x[t] = esum[t - 256];
  __syncthreads();
  if (t < 256) {
    float a = bb1[t];
    for (int k = 0; k < 384; ++k) a = fmaf(x[k], w1[k * 256 + t], a);
    h1[t] = fmaxf(a, 0.f);
  }
  __syncthreads();
  if (t < 256) {
    float a = bb2[t];
    for (int k = 0; k < 256; ++k) a = fmaf(h1[k], w2[k * 256 + t], a);
    h2[t] = fmaxf(a, 0.f);
  }
  __syncthreads();
  if (t < 256) {
    float a = bb3[t];
    for (int k = 0; k < 256; ++k) a = fmaf(h2[k], w3[k * 256 + t], a);
    h3[t] = fmaxf(a, 0.f);
  }
  __syncthreads();
  if (t < 128) {
    float a = bb4[t];
    for (int k = 0; k < 256; ++k) a = fmaf(h3[k], w4[k * 128 + t], a);
    outg[t] = a;
  }
}

extern "C" void kernel_launch(void* const* d_in, const int* in_sizes, int n_in, void* d_out,
                              int out_size, void* d_ws, size_t ws_size, hipStream_t stream) {
  const float* g = (const float*)d_in[0];
  const float* nodes = (const float*)d_in[1];
  const float* edges = (const float*)d_in[2];
  const int* senders = (const int*)d_in[3];
  const int* receivers = (const int*)d_in[4];
  const float* ew[4] = {(const float*)d_in[5], (const float*)d_in[7], (const float*)d_in[9],
                        (const float*)d_in[11]};
  const float* eb[4] = {(const float*)d_in[6], (const float*)d_in[8], (const float*)d_in[10],
                        (const float*)d_in[12]};
  const float* nw[4] = {(const float*)d_in[13], (const float*)d_in[15], (const float*)d_in[17],
                        (const float*)d_in[19]};
  const float* nb[4] = {(const float*)d_in[14], (const float*)d_in[16], (const float*)d_in[18],
                        (const float*)d_in[20]};
  const float* gw[4] = {(const float*)d_in[21], (const float*)d_in[23], (const float*)d_in[25],
                        (const float*)d_in[27]};
  const float* gb[4] = {(const float*)d_in[22], (const float*)d_in[24], (const float*)d_in[26],
                        (const float*)d_in[28]};

  float* out = (float*)d_out;
  float* e_new = out;
  float* n_new = out + (size_t)NE * 128;
  float* g_new = n_new + (size_t)NNODES * 128;

  // workspace layout
  char* ws = (char*)d_ws;
  unsigned short* pe1 = (unsigned short*)ws;           // 512x256
  unsigned short* pe2 = pe1 + 512 * 256;               // 256x256
  unsigned short* pe3 = pe2 + 256 * 256;               // 256x256
  unsigned short* pe4 = pe3 + 256 * 256;               // 256x128
  unsigned short* pn1 = pe4 + 256 * 128;               // 384x256
  unsigned short* pn2 = pn1 + 384 * 256;               // 256x256
  unsigned short* pn3 = pn2 + 256 * 256;               // 256x256
  unsigned short* pn4 = pn3 + 256 * 256;               // 256x128
  float* agg = (float*)(ws + 1114112);                 // 20000x128 fp32
  float* esum = agg + (size_t)NNODES * 128;            // 128
  float* nsum = esum + 128;                            // 128

  hipMemsetAsync(agg, 0, (size_t)NNODES * 128 * 4 + 1024, stream);

  PackArgs pa;
  const float* srcs[8] = {ew[0], ew[1], ew[2], ew[3], nw[0], nw[1], nw[2], nw[3]};
  unsigned short* dsts[8] = {pe1, pe2, pe3, pe4, pn1, pn2, pn3, pn4};
  int Ks[8] = {512, 256, 256, 256, 384, 256, 256, 256};
  int Ns[8] = {256, 256, 256, 128, 256, 256, 256, 128};
  for (int i = 0; i < 8; ++i) {
    pa.src[i] = srcs[i];
    pa.dst[i] = dsts[i];
    pa.K[i] = Ks[i];
    pa.N[i] = Ns[i];
  }
  pack_weights<<<dim3(64, 8), 256, 0, stream>>>(pa);

  hipFuncSetAttribute((const void*)&fused_mlp<0>, hipFuncAttributeMaxDynamicSharedMemorySize,
                      SMEM_BYTES);
  hipFuncSetAttribute((const void*)&fused_mlp<1>, hipFuncAttributeMaxDynamicSharedMemorySize,
                      SMEM_BYTES);

  fused_mlp<0><<<NE / 128, 512, SMEM_BYTES, stream>>>(
      g, nodes, edges, senders, receivers, pe1, pe2, pe3, pe4, eb[0], eb[1], eb[2], eb[3], e_new,
      agg, esum);
  fused_mlp<1><<<(NNODES + 127) / 128, 512, SMEM_BYTES, stream>>>(
      g, nodes, agg, senders, receivers, pn1, pn2, pn3, pn4, nb[0], nb[1], nb[2], nb[3], n_new,
      nullptr, nsum);
  global_mlp<<<1, 384, 0, stream>>>(g, nsum, esum, gw[0], gb[0], gw[1], gb[1], gw[2], gb[2], gw[3],
                                    gb[3], g_new);
}